// Round 1
// 152.898 us; speedup vs baseline: 1.1611x; 1.1611x over previous
//
#include <hip/hip_runtime.h>
#include <math.h>

// Problem constants
#define NB 32
#define NC 64          // CODE_DIM
#define NK 2048
#define NCODES 1024
#define NVEC (NB*NK)          // 65536 vectors
#define NELEM (NB*NC*NK)      // 4194304 elements
#define NBLK (NVEC/64)        // 1024 blocks

#define MARGIN 1.5e-3f        // rigorous bf16-proxy bound (validated R5)
#define CAP 32

// ws layout (bytes)
#define WS_HIST  0            // int[1024]      = 4096
#define WS_CBN32 4096         // float[1024]    = 4096
#define WS_PART  8192         // double[1024]   = 8192
#define WS_CBBF  32768        // __bf16[65536]  = 131072

typedef __bf16 bf16x8 __attribute__((ext_vector_type(8)));
typedef float  f32x4  __attribute__((ext_vector_type(4)));
#define MFMA16(A, B, ACC) __builtin_amdgcn_mfma_f32_16x16x32_bf16(A, B, ACC, 0, 0, 0)

// --- codebook prep: numpy-exact fp32 norms (same summation order as validated
// version -> bit-identical n32) + bf16 copy. Vectorized loads/stores; also
// zeroes hist (block 0) so the separate memset dispatch is gone. -------------
__global__ void k_cbprep(const float* __restrict__ cb, float* __restrict__ n32,
                         __bf16* __restrict__ cbbf, int* __restrict__ hist) {
    const int t = threadIdx.x;
    const int j = blockIdx.x * 64 + t;   // 16 x 64 = 1024
    if (blockIdx.x == 0) {
        int4 z4; z4.x = 0; z4.y = 0; z4.z = 0; z4.w = 0;
#pragma unroll
        for (int i = 0; i < 4; i++) ((int4*)hist)[t * 4 + i] = z4;
    }
    const float* cr = cb + (size_t)j * NC;
    float x[64];
#pragma unroll
    for (int i = 0; i < 16; i++) {
        f32x4 tv = *(const f32x4*)(cr + 4 * i);
        x[4*i+0] = tv[0]; x[4*i+1] = tv[1]; x[4*i+2] = tv[2]; x[4*i+3] = tv[3];
    }
    // EXACT same chain as validated version (order preserved)
    float r[8];
#pragma unroll
    for (int q = 0; q < 8; q++) r[q] = __fmul_rn(x[q], x[q]);
#pragma unroll
    for (int i = 8; i < 64; i += 8)
#pragma unroll
        for (int q = 0; q < 8; q++)
            r[q] = __fadd_rn(r[q], __fmul_rn(x[i + q], x[i + q]));
    float s01 = __fadd_rn(r[0], r[1]), s23 = __fadd_rn(r[2], r[3]);
    float s45 = __fadd_rn(r[4], r[5]), s67 = __fadd_rn(r[6], r[7]);
    n32[j] = __fadd_rn(__fadd_rn(s01, s23), __fadd_rn(s45, s67));
    __bf16* br = cbbf + (size_t)j * NC;
#pragma unroll
    for (int i = 0; i < 8; i++) {
        bf16x8 o;
#pragma unroll
        for (int q = 0; q < 8; q++) o[q] = (__bf16)x[8*i + q];
        *(bf16x8*)(br + 8*i) = o;
    }
}

// --- fused VQ, restructured ------------------------------------------------
// Block: 512 thr = 8 waves; 64 vectors. Wave w owns codes [w*128, w*128+128)
// (8 tiles of 16) held as B-frags in VGPRs for BOTH passes; A-frags for all 64
// vectors also reg-resident. Pass 1: pure MFMA+fmin per-lane min (no shuffles,
// no atomics, no memory in loop). One cross-lane reduce + LDS merge -> global
// proxy min per vector. Pass 2: recompute pd (MFMA is ~3% util, recompute is
// free), capture {pd <= gmin + MARGIN} -- exactly the sufficient set the
// validated running-min capture was a superset of. Exact fp32 rescore chain
// unchanged (bit-identical to validated R5 version).
// MFMA 16x16x32 bf16 layout (validated R5): A[m=lane&15][k=quad*8+j];
// B[n=lane&15][k=quad*8+j]; D col=lane&15, row=quad*4+reg.
__launch_bounds__(512, 2)
__global__ void k_vq(const float* __restrict__ ze, const float* __restrict__ cb,
                     const float* __restrict__ n32, const __bf16* __restrict__ cbbf,
                     int* __restrict__ hist, float* __restrict__ codes_f,
                     float* __restrict__ outq, double* __restrict__ part) {
    __shared__ float wmin[64][8];
    __shared__ float gthr[64];
    __shared__ int cnt[64];
    __shared__ int cand[64][CAP];
    __shared__ unsigned long long keys2[64][8];
    __shared__ int codearr[64];
    __shared__ double lsd[8];

    const int t = threadIdx.x;
    const int L = t & 63;
    const int w = t >> 6;            // wave 0..7
    const int quad = L >> 4;
    const int col = L & 15;
    const int vec0 = blockIdx.x * 64;
    const int b = vec0 >> 11;
    const int k0 = vec0 & (NK - 1);
    const float* zbase = ze + (size_t)b * NC * NK + k0;

    // ---- stage: B-frags (this wave's 128 codes) + norms + A-frags (64 vecs)
    bf16x8 bfr[8][2];
    float n32v[8];
#pragma unroll
    for (int tile = 0; tile < 8; tile++) {
        const __bf16* brow = cbbf + (size_t)(w*128 + tile*16 + col) * NC + quad*8;
        bfr[tile][0] = *(const bf16x8*)(brow);
        bfr[tile][1] = *(const bf16x8*)(brow + 32);
        n32v[tile] = n32[w*128 + tile*16 + col];
    }
    bf16x8 af[4][2];
#pragma unroll
    for (int vt = 0; vt < 4; vt++)
#pragma unroll
        for (int kt = 0; kt < 2; kt++)
#pragma unroll
            for (int j = 0; j < 8; j++)
                af[vt][kt][j] =
                    (__bf16)zbase[(size_t)(kt*32 + quad*8 + j) * NK + vt*16 + col];

    // ---- pass 1: per-lane proxy min over wave's codes (reg-only hot loop) --
    float pmin[4][4];
#pragma unroll
    for (int vt = 0; vt < 4; vt++)
#pragma unroll
        for (int r = 0; r < 4; r++) pmin[vt][r] = 1e30f;
#pragma unroll
    for (int tile = 0; tile < 8; tile++) {
#pragma unroll
        for (int vt = 0; vt < 4; vt++) {   // 4 independent MFMA chains (ILP)
            f32x4 acc = {0.f, 0.f, 0.f, 0.f};
            acc = MFMA16(af[vt][0], bfr[tile][0], acc);
            acc = MFMA16(af[vt][1], bfr[tile][1], acc);
#pragma unroll
            for (int r = 0; r < 4; r++) {
                float pd = __fsub_rn(n32v[tile], __fmul_rn(2.f, acc[r]));
                pmin[vt][r] = fminf(pmin[vt][r], pd);
            }
        }
    }
    // one-time cross-col reduce (vs per-tile in the old kernel: 64 shfl not 1024)
#pragma unroll
    for (int vt = 0; vt < 4; vt++)
#pragma unroll
        for (int r = 0; r < 4; r++) {
            float pm = pmin[vt][r];
            pm = fminf(pm, __shfl_xor(pm, 1, 16));
            pm = fminf(pm, __shfl_xor(pm, 2, 16));
            pm = fminf(pm, __shfl_xor(pm, 4, 16));
            pm = fminf(pm, __shfl_xor(pm, 8, 16));
            if (col == 0) wmin[vt*16 + quad*4 + r][w] = pm;
        }
    __syncthreads();

    if (t < 64) {
        float g = wmin[t][0];
#pragma unroll
        for (int ww = 1; ww < 8; ww++) g = fminf(g, wmin[t][ww]);
        gthr[t] = g + MARGIN;
        cnt[t] = 0;
    }
    __syncthreads();

    // ---- pass 2: capture candidates within MARGIN of global proxy min ------
    float thr[4][4];
#pragma unroll
    for (int vt = 0; vt < 4; vt++)
#pragma unroll
        for (int r = 0; r < 4; r++) thr[vt][r] = gthr[vt*16 + quad*4 + r];
#pragma unroll
    for (int tile = 0; tile < 8; tile++) {
#pragma unroll
        for (int vt = 0; vt < 4; vt++) {
            f32x4 acc = {0.f, 0.f, 0.f, 0.f};
            acc = MFMA16(af[vt][0], bfr[tile][0], acc);
            acc = MFMA16(af[vt][1], bfr[tile][1], acc);
#pragma unroll
            for (int r = 0; r < 4; r++) {
                float pd = __fsub_rn(n32v[tile], __fmul_rn(2.f, acc[r]));
                if (pd <= thr[vt][r]) {
                    int m = vt*16 + quad*4 + r;
                    int slot = atomicAdd(&cnt[m], 1);
                    if (slot < CAP) cand[m][slot] = w*128 + tile*16 + col;
                }
            }
        }
    }
    __syncthreads();

    // ---- exact rescore: 8 threads/vector, validated bit-exact fp32 chain ---
    {
        const int v = L;               // vector; this thread handles part w
        float rr[8];
#pragma unroll
        for (int q = 0; q < 8; q++) {
            float xx = zbase[(size_t)q * NK + v];
            rr[q] = __fmul_rn(xx, xx);
        }
#pragma unroll
        for (int i = 8; i < 64; i += 8)
#pragma unroll
            for (int q = 0; q < 8; q++) {
                float xx = zbase[(size_t)(i + q) * NK + v];
                rr[q] = __fadd_rn(rr[q], __fmul_rn(xx, xx));
            }
        float s01 = __fadd_rn(rr[0], rr[1]), s23 = __fadd_rn(rr[2], rr[3]);
        float s45 = __fadd_rn(rr[4], rr[5]), s67 = __fadd_rn(rr[6], rr[7]);
        float t1 = __fadd_rn(__fadd_rn(s01, s23), __fadd_rn(s45, s67));

        int cc = cnt[v];
        unsigned long long kmin = 0xFFFFFFFFFFFFFFFFULL;
        if (cc <= CAP) {
            for (int si = w; si < cc; si += 8) {
                int j = cand[v][si];
                const float* cr = cb + (size_t)j * NC;
                float a = 0.f;
#pragma unroll
                for (int c = 0; c < NC; c++)
                    a = __fmaf_rn(zbase[(size_t)c * NK + v], cr[c], a);
                float d = __fsub_rn(__fadd_rn(t1, n32[j]), __fmul_rn(2.f, a));
                unsigned long long key =
                    ((unsigned long long)__float_as_uint(d) << 32) | (unsigned int)j;
                if (key < kmin) kmin = key;
            }
        } else {   // overflow fallback: exact full scan split over 8 threads
            for (int j = w * 128; j < (w + 1) * 128; j++) {
                const float* cr = cb + (size_t)j * NC;
                float a = 0.f;
#pragma unroll
                for (int c = 0; c < NC; c++)
                    a = __fmaf_rn(zbase[(size_t)c * NK + v], cr[c], a);
                float d = __fsub_rn(__fadd_rn(t1, n32[j]), __fmul_rn(2.f, a));
                unsigned long long key =
                    ((unsigned long long)__float_as_uint(d) << 32) | (unsigned int)j;
                if (key < kmin) kmin = key;
            }
        }
        keys2[v][w] = kmin;
    }
    __syncthreads();

    if (t < 64) {   // merge 8 partial keys: min dist, ties -> min idx (np rule)
        unsigned long long kmin = keys2[t][0];
#pragma unroll
        for (int ww = 1; ww < 8; ww++) {
            unsigned long long kk = keys2[t][ww];
            if (kk < kmin) kmin = kk;
        }
        int code = (int)(kmin & 0xFFFFFFFFu);
        codearr[t] = code;
        codes_f[vec0 + t] = (float)code;
        atomicAdd(&hist[code], 1);
    }
    __syncthreads();

    // ---- quant epilogue: float4 over vectors; thread covers c0 and c0+32 ---
    double s = 0.0;
    float* ob = outq + (size_t)b * NC * NK + k0;
    const int c0 = t >> 4;             // 0..31
    const int v0 = (t & 15) * 4;       // 0,4,..,60
    int cds[4];
#pragma unroll
    for (int u = 0; u < 4; u++) cds[u] = codearr[v0 + u];
#pragma unroll
    for (int half = 0; half < 2; half++) {
        const int c = c0 + half * 32;
        f32x4 zv = *(const f32x4*)(zbase + (size_t)c * NK + v0);
        f32x4 ov;
#pragma unroll
        for (int u = 0; u < 4; u++) {
            float qv = cb[(size_t)cds[u] * NC + c];
            ov[u] = __fadd_rn(zv[u], __fsub_rn(qv, zv[u]));
            double d = (double)qv - (double)zv[u];
            s += d * d;
        }
        *(f32x4*)(ob + (size_t)c * NK + v0) = ov;
    }
    for (int off = 32; off; off >>= 1) s += __shfl_down(s, off);
    if (L == 0) lsd[w] = s;
    __syncthreads();
    if (t == 0) {
        double tot = 0.0;
#pragma unroll
        for (int i = 0; i < 8; i++) tot += lsd[i];
        part[blockIdx.x] = tot;
    }
}

// --- final scalars: loss_vq and perplexity ----------------------------------
__launch_bounds__(1024)
__global__ void k_final(const double* __restrict__ part, const int* __restrict__ hist,
                        float* __restrict__ out) {
    int t = threadIdx.x;                         // 1024 threads = NBLK partials
    double vL = part[t];
    double p = (double)hist[t] * (1.0 / (double)NVEC);
    double vE = p * log(p + 1e-10);
    for (int off = 32; off; off >>= 1) {
        vL += __shfl_down(vL, off);
        vE += __shfl_down(vE, off);
    }
    __shared__ double lsL[16], lsE[16];
    int lane = t & 63, wv = t >> 6;
    if (lane == 0) { lsL[wv] = vL; lsE[wv] = vE; }
    __syncthreads();
    if (t == 0) {
        double SL = 0.0, SE = 0.0;
        for (int i = 0; i < 16; i++) { SL += lsL[i]; SE += lsE[i]; }
        double loss_cb = SL / (double)NELEM;     // == loss_commit numerically
        out[NELEM + NVEC]     = (float)(loss_cb + 0.25 * loss_cb);
        out[NELEM + NVEC + 1] = (float)exp(-SE);
    }
}

extern "C" void kernel_launch(void* const* d_in, const int* in_sizes, int n_in,
                              void* d_out, int out_size, void* d_ws, size_t ws_size,
                              hipStream_t stream) {
    const float* ze = (const float*)d_in[0];
    const float* cb = (const float*)d_in[1];
    float* out = (float*)d_out;
    char* ws = (char*)d_ws;

    int*    hist = (int*)(ws + WS_HIST);
    float*  n32  = (float*)(ws + WS_CBN32);
    double* part = (double*)(ws + WS_PART);
    __bf16* cbbf = (__bf16*)(ws + WS_CBBF);

    float* zq      = out;                 // (32, 64, 2048)
    float* codes_f = out + NELEM;         // (32, 2048) as float

    k_cbprep<<<16, 64, 0, stream>>>(cb, n32, cbbf, hist);   // also zeroes hist
    k_vq<<<NBLK, 512, 0, stream>>>(ze, cb, n32, cbbf, hist, codes_f, zq, part);
    k_final<<<1, 1024, 0, stream>>>(part, hist, out);
}

// Round 2
// 128.407 us; speedup vs baseline: 1.3825x; 1.1907x over previous
//
#include <hip/hip_runtime.h>
#include <math.h>

// Problem constants
#define NB 32
#define NC 64          // CODE_DIM
#define NK 2048
#define NCODES 1024
#define NVEC (NB*NK)          // 65536 vectors
#define NELEM (NB*NC*NK)      // 4194304 elements
#define NBLK (NVEC/64)        // 1024 blocks

#define MARGIN 1.5e-3f        // rigorous bf16-proxy bound (validated R5)
#define CAP 32

// ws layout (bytes)
#define WS_HIST  0            // int[1024]      = 4096
#define WS_CBN32 4096         // float[1024]    = 4096
#define WS_PART  8192         // double[1024]   = 8192
#define WS_CBBF  32768        // __bf16[65536]  = 131072

typedef __bf16 bf16x8 __attribute__((ext_vector_type(8)));
typedef float  f32x4  __attribute__((ext_vector_type(4)));
#define MFMA16(A, B, ACC) __builtin_amdgcn_mfma_f32_16x16x32_bf16(A, B, ACC, 0, 0, 0)

// --- codebook prep: numpy-exact fp32 norms (same summation order as validated
// version -> bit-identical n32) + bf16 copy; block 0 zeroes hist. -------------
__global__ void k_cbprep(const float* __restrict__ cb, float* __restrict__ n32,
                         __bf16* __restrict__ cbbf, int* __restrict__ hist) {
    const int t = threadIdx.x;
    const int j = blockIdx.x * 64 + t;   // 16 x 64 = 1024
    if (blockIdx.x == 0) {
        int4 z4; z4.x = 0; z4.y = 0; z4.z = 0; z4.w = 0;
#pragma unroll
        for (int i = 0; i < 4; i++) ((int4*)hist)[t * 4 + i] = z4;
    }
    const float* cr = cb + (size_t)j * NC;
    float x[64];
#pragma unroll
    for (int i = 0; i < 16; i++) {
        f32x4 tv = *(const f32x4*)(cr + 4 * i);
        x[4*i+0] = tv[0]; x[4*i+1] = tv[1]; x[4*i+2] = tv[2]; x[4*i+3] = tv[3];
    }
    // EXACT same chain as validated version (order preserved)
    float r[8];
#pragma unroll
    for (int q = 0; q < 8; q++) r[q] = __fmul_rn(x[q], x[q]);
#pragma unroll
    for (int i = 8; i < 64; i += 8)
#pragma unroll
        for (int q = 0; q < 8; q++)
            r[q] = __fadd_rn(r[q], __fmul_rn(x[i + q], x[i + q]));
    float s01 = __fadd_rn(r[0], r[1]), s23 = __fadd_rn(r[2], r[3]);
    float s45 = __fadd_rn(r[4], r[5]), s67 = __fadd_rn(r[6], r[7]);
    n32[j] = __fadd_rn(__fadd_rn(s01, s23), __fadd_rn(s45, s67));
    __bf16* br = cbbf + (size_t)j * NC;
#pragma unroll
    for (int i = 0; i < 8; i++) {
        bf16x8 o;
#pragma unroll
        for (int q = 0; q < 8; q++) o[q] = (__bf16)x[8*i + q];
        *(bf16x8*)(br + 8*i) = o;
    }
}

// --- fused VQ, full-residency version ---------------------------------------
// Block: 256 thr = 4 waves; 64 vectors. Grid = 1024 blocks -> 4096 waves total
// = 4 waves/SIMD device-wide: the ENTIRE grid is co-resident in one round
// (VGPR budget <=128 enforced by __launch_bounds__(256,4)), so latency stalls
// overlap across blocks instead of serializing over residency rounds (the R1
// failure: 124 VGPR x 8-wave blocks -> 1 block/CU, 4 rounds, 21% occupancy).
// Wave w owns codes [w*256, w*256+256) = 16 tiles, B-frags STREAMED from L2
// per tile (not reg-resident; per-block 256 KB L2 traffic, ~7 us grid-wide
// aggregate at L2 BW, fully overlapped). A-frags reg-resident (32 VGPR).
// Pass 1: per-lane proxy min (no shuffles/atomics/LDS in loop). One cross-lane
// reduce + LDS merge -> global proxy min. Pass 2: recompute pd (identical
// operands -> bit-identical MFMA), capture {pd <= gmin + MARGIN} -- same
// sufficient set as validated. Exact fp32 rescore chain unchanged.
// MFMA 16x16x32 bf16 layout (validated R5): A[m=lane&15][k=quad*8+j];
// B[n=lane&15][k=quad*8+j]; D col=lane&15, row=quad*4+reg.
__launch_bounds__(256, 4)
__global__ void k_vq(const float* __restrict__ ze, const float* __restrict__ cb,
                     const float* __restrict__ n32, const __bf16* __restrict__ cbbf,
                     int* __restrict__ hist, float* __restrict__ codes_f,
                     float* __restrict__ outq, double* __restrict__ part) {
    __shared__ float wmin[64][4];
    __shared__ float gthr[64];
    __shared__ int cnt[64];
    __shared__ int cand[64][CAP];
    __shared__ unsigned long long keys2[64][4];
    __shared__ int codearr[64];
    __shared__ double lsd[4];

    const int t = threadIdx.x;
    const int L = t & 63;
    const int w = t >> 6;            // wave 0..3
    const int quad = L >> 4;
    const int col = L & 15;
    const int vec0 = blockIdx.x * 64;
    const int b = vec0 >> 11;
    const int k0 = vec0 & (NK - 1);
    const float* zbase = ze + (size_t)b * NC * NK + k0;

    // ---- stage: A-frags for all 64 vectors (reg-resident, 32 VGPR) ---------
    bf16x8 af[4][2];
#pragma unroll
    for (int vt = 0; vt < 4; vt++)
#pragma unroll
        for (int kt = 0; kt < 2; kt++)
#pragma unroll
            for (int j = 0; j < 8; j++)
                af[vt][kt][j] =
                    (__bf16)zbase[(size_t)(kt*32 + quad*8 + j) * NK + vt*16 + col];

    // ---- pass 1: per-lane proxy min over wave's 256 codes ------------------
    float pmin[4][4];
#pragma unroll
    for (int vt = 0; vt < 4; vt++)
#pragma unroll
        for (int r = 0; r < 4; r++) pmin[vt][r] = 1e30f;
#pragma unroll 4
    for (int tile = 0; tile < 16; tile++) {   // unroll 4: limit B-load hoisting
        const __bf16* brow = cbbf + (size_t)(w*256 + tile*16 + col) * NC + quad*8;
        bf16x8 b0 = *(const bf16x8*)(brow);
        bf16x8 b1 = *(const bf16x8*)(brow + 32);
        float nvv = n32[w*256 + tile*16 + col];
#pragma unroll
        for (int vt = 0; vt < 4; vt++) {   // 4 independent MFMA chains (ILP)
            f32x4 acc = {0.f, 0.f, 0.f, 0.f};
            acc = MFMA16(af[vt][0], b0, acc);
            acc = MFMA16(af[vt][1], b1, acc);
#pragma unroll
            for (int r = 0; r < 4; r++) {
                float pd = __fsub_rn(nvv, __fmul_rn(2.f, acc[r]));
                pmin[vt][r] = fminf(pmin[vt][r], pd);
            }
        }
    }
    // one-time cross-col reduce
#pragma unroll
    for (int vt = 0; vt < 4; vt++)
#pragma unroll
        for (int r = 0; r < 4; r++) {
            float pm = pmin[vt][r];
            pm = fminf(pm, __shfl_xor(pm, 1, 16));
            pm = fminf(pm, __shfl_xor(pm, 2, 16));
            pm = fminf(pm, __shfl_xor(pm, 4, 16));
            pm = fminf(pm, __shfl_xor(pm, 8, 16));
            if (col == 0) wmin[vt*16 + quad*4 + r][w] = pm;
        }
    __syncthreads();

    if (t < 64) {
        float g = wmin[t][0];
#pragma unroll
        for (int ww = 1; ww < 4; ww++) g = fminf(g, wmin[t][ww]);
        gthr[t] = g + MARGIN;
        cnt[t] = 0;
    }
    __syncthreads();

    // ---- pass 2: capture candidates within MARGIN of global proxy min ------
    float thr[4][4];
#pragma unroll
    for (int vt = 0; vt < 4; vt++)
#pragma unroll
        for (int r = 0; r < 4; r++) thr[vt][r] = gthr[vt*16 + quad*4 + r];
#pragma unroll 4
    for (int tile = 0; tile < 16; tile++) {
        const __bf16* brow = cbbf + (size_t)(w*256 + tile*16 + col) * NC + quad*8;
        bf16x8 b0 = *(const bf16x8*)(brow);
        bf16x8 b1 = *(const bf16x8*)(brow + 32);
        float nvv = n32[w*256 + tile*16 + col];
#pragma unroll
        for (int vt = 0; vt < 4; vt++) {
            f32x4 acc = {0.f, 0.f, 0.f, 0.f};
            acc = MFMA16(af[vt][0], b0, acc);
            acc = MFMA16(af[vt][1], b1, acc);
#pragma unroll
            for (int r = 0; r < 4; r++) {
                float pd = __fsub_rn(nvv, __fmul_rn(2.f, acc[r]));
                if (pd <= thr[vt][r]) {
                    int m = vt*16 + quad*4 + r;
                    int slot = atomicAdd(&cnt[m], 1);
                    if (slot < CAP) cand[m][slot] = w*256 + tile*16 + col;
                }
            }
        }
    }
    __syncthreads();

    // ---- exact rescore: 4 threads/vector, validated bit-exact fp32 chain ---
    {
        const int v = L;               // vector; this thread handles part w
        float rr[8];
#pragma unroll
        for (int q = 0; q < 8; q++) {
            float xx = zbase[(size_t)q * NK + v];
            rr[q] = __fmul_rn(xx, xx);
        }
#pragma unroll
        for (int i = 8; i < 64; i += 8)
#pragma unroll
            for (int q = 0; q < 8; q++) {
                float xx = zbase[(size_t)(i + q) * NK + v];
                rr[q] = __fadd_rn(rr[q], __fmul_rn(xx, xx));
            }
        float s01 = __fadd_rn(rr[0], rr[1]), s23 = __fadd_rn(rr[2], rr[3]);
        float s45 = __fadd_rn(rr[4], rr[5]), s67 = __fadd_rn(rr[6], rr[7]);
        float t1 = __fadd_rn(__fadd_rn(s01, s23), __fadd_rn(s45, s67));

        int cc = cnt[v];
        unsigned long long kmin = 0xFFFFFFFFFFFFFFFFULL;
        if (cc <= CAP) {
            for (int si = w; si < cc; si += 4) {
                int j = cand[v][si];
                const float* cr = cb + (size_t)j * NC;
                float a = 0.f;
#pragma unroll
                for (int c = 0; c < NC; c++)
                    a = __fmaf_rn(zbase[(size_t)c * NK + v], cr[c], a);
                float d = __fsub_rn(__fadd_rn(t1, n32[j]), __fmul_rn(2.f, a));
                unsigned long long key =
                    ((unsigned long long)__float_as_uint(d) << 32) | (unsigned int)j;
                if (key < kmin) kmin = key;
            }
        } else {   // overflow fallback: exact full scan split over 4 threads
            for (int j = w * 256; j < (w + 1) * 256; j++) {
                const float* cr = cb + (size_t)j * NC;
                float a = 0.f;
#pragma unroll
                for (int c = 0; c < NC; c++)
                    a = __fmaf_rn(zbase[(size_t)c * NK + v], cr[c], a);
                float d = __fsub_rn(__fadd_rn(t1, n32[j]), __fmul_rn(2.f, a));
                unsigned long long key =
                    ((unsigned long long)__float_as_uint(d) << 32) | (unsigned int)j;
                if (key < kmin) kmin = key;
            }
        }
        keys2[v][w] = kmin;
    }
    __syncthreads();

    if (t < 64) {   // merge 4 partial keys: min dist, ties -> min idx (np rule)
        unsigned long long kmin = keys2[t][0];
#pragma unroll
        for (int ww = 1; ww < 4; ww++) {
            unsigned long long kk = keys2[t][ww];
            if (kk < kmin) kmin = kk;
        }
        int code = (int)(kmin & 0xFFFFFFFFu);
        codearr[t] = code;
        codes_f[vec0 + t] = (float)code;
        atomicAdd(&hist[code], 1);
    }
    __syncthreads();

    // ---- quant epilogue: float4 over vectors; thread covers 4 c's ----------
    double s = 0.0;
    float* ob = outq + (size_t)b * NC * NK + k0;
    const int c0 = t >> 4;             // 0..15
    const int v0 = (t & 15) * 4;       // 0,4,..,60
    int cds[4];
#pragma unroll
    for (int u = 0; u < 4; u++) cds[u] = codearr[v0 + u];
#pragma unroll
    for (int half = 0; half < 4; half++) {
        const int c = c0 + half * 16;
        f32x4 zv = *(const f32x4*)(zbase + (size_t)c * NK + v0);
        f32x4 ov;
#pragma unroll
        for (int u = 0; u < 4; u++) {
            float qv = cb[(size_t)cds[u] * NC + c];
            ov[u] = __fadd_rn(zv[u], __fsub_rn(qv, zv[u]));
            double d = (double)qv - (double)zv[u];
            s += d * d;
        }
        *(f32x4*)(ob + (size_t)c * NK + v0) = ov;
    }
    for (int off = 32; off; off >>= 1) s += __shfl_down(s, off);
    if (L == 0) lsd[w] = s;
    __syncthreads();
    if (t == 0) {
        double tot = 0.0;
#pragma unroll
        for (int i = 0; i < 4; i++) tot += lsd[i];
        part[blockIdx.x] = tot;
    }
}

// --- final scalars: loss_vq and perplexity ----------------------------------
__launch_bounds__(1024)
__global__ void k_final(const double* __restrict__ part, const int* __restrict__ hist,
                        float* __restrict__ out) {
    int t = threadIdx.x;                         // 1024 threads = NBLK partials
    double vL = part[t];
    double p = (double)hist[t] * (1.0 / (double)NVEC);
    double vE = p * log(p + 1e-10);
    for (int off = 32; off; off >>= 1) {
        vL += __shfl_down(vL, off);
        vE += __shfl_down(vE, off);
    }
    __shared__ double lsL[16], lsE[16];
    int lane = t & 63, wv = t >> 6;
    if (lane == 0) { lsL[wv] = vL; lsE[wv] = vE; }
    __syncthreads();
    if (t == 0) {
        double SL = 0.0, SE = 0.0;
        for (int i = 0; i < 16; i++) { SL += lsL[i]; SE += lsE[i]; }
        double loss_cb = SL / (double)NELEM;     // == loss_commit numerically
        out[NELEM + NVEC]     = (float)(loss_cb + 0.25 * loss_cb);
        out[NELEM + NVEC + 1] = (float)exp(-SE);
    }
}

extern "C" void kernel_launch(void* const* d_in, const int* in_sizes, int n_in,
                              void* d_out, int out_size, void* d_ws, size_t ws_size,
                              hipStream_t stream) {
    const float* ze = (const float*)d_in[0];
    const float* cb = (const float*)d_in[1];
    float* out = (float*)d_out;
    char* ws = (char*)d_ws;

    int*    hist = (int*)(ws + WS_HIST);
    float*  n32  = (float*)(ws + WS_CBN32);
    double* part = (double*)(ws + WS_PART);
    __bf16* cbbf = (__bf16*)(ws + WS_CBBF);

    float* zq      = out;                 // (32, 64, 2048)
    float* codes_f = out + NELEM;         // (32, 2048) as float

    k_cbprep<<<16, 64, 0, stream>>>(cb, n32, cbbf, hist);   // also zeroes hist
    k_vq<<<NBLK, 256, 0, stream>>>(ze, cb, n32, cbbf, hist, codes_f, zq, part);
    k_final<<<1, 1024, 0, stream>>>(part, hist, out);
}